// Round 1
// baseline (1651.583 us; speedup 1.0000x reference)
//
#include <hip/hip_runtime.h>
#include <cstddef>

#define C_    128
#define DW_   256
#define HW_   (192 * 192)
#define B_    8
#define NPIX_ (B_ * HW_)
#define EPS_  1e-6f

__device__ __forceinline__ float4 ld4(const float* p) { return *(const float4*)p; }

// ---------------------------------------------------------------------------
// Phase 1: LN1 -> w1 matmul -> depthwise affine -> SimpleGate -> sg (to d_out
// scratch) + per-batch gap partial sums (atomic).
// Block = 256 threads, 8 pixels per block.
// ---------------------------------------------------------------------------
__global__ __launch_bounds__(256) void k_phase1(
    const float* __restrict__ x,
    const float* __restrict__ ln1s, const float* __restrict__ ln1b,
    const float* __restrict__ w1,   const float* __restrict__ b1,
    const float* __restrict__ wdw,  const float* __restrict__ bdw,
    float* __restrict__ sg_out,     // aliases d_out (scratch)
    float* __restrict__ gap)        // [B_][C_] in d_ws, pre-zeroed
{
    __shared__ float sn[8][C_];     // LN1 output
    __shared__ float gbuf[256];     // per-thread gap partials

    const int tid   = threadIdx.x;
    const int pix0  = blockIdx.x * 8;
    const int batch = pix0 / HW_;   // 8 | HW_, so whole block in one batch

    // ---- load + LayerNorm1 (32 threads per pixel, 4 ch each) ----
    {
        const int p  = tid >> 5;
        const int c0 = (tid & 31) << 2;
        const float4 x4 = ld4(x + (size_t)(pix0 + p) * C_ + c0);
        float s  = x4.x + x4.y + x4.z + x4.w;
        float ss = x4.x * x4.x + x4.y * x4.y + x4.z * x4.z + x4.w * x4.w;
        #pragma unroll
        for (int m = 16; m >= 1; m >>= 1) {
            s  += __shfl_xor(s,  m, 32);
            ss += __shfl_xor(ss, m, 32);
        }
        const float mu  = s * (1.0f / C_);
        const float var = ss * (1.0f / C_) - mu * mu;
        const float r   = rsqrtf(var + EPS_);
        const float4 sc = ld4(ln1s + c0);
        const float4 bi = ld4(ln1b + c0);
        float4 o;
        o.x = (x4.x - mu) * r * sc.x + bi.x;
        o.y = (x4.y - mu) * r * sc.y + bi.y;
        o.z = (x4.z - mu) * r * sc.z + bi.z;
        o.w = (x4.w - mu) * r * sc.w + bi.w;
        *(float4*)(&sn[p][c0]) = o;
    }
    __syncthreads();

    // ---- matmul C->2C; thread owns gate pair (c, c+128) for 4 pixels ----
    const int c  = tid & 127;
    const int pg = tid >> 7;          // pixel group: 0 -> pixels 0..3, 1 -> 4..7
    float acc0[4] = {0.f, 0.f, 0.f, 0.f};
    float acc1[4] = {0.f, 0.f, 0.f, 0.f};
    for (int k = 0; k < C_; k += 4) {
        const float wa0 = w1[(k + 0) * DW_ + c];
        const float wa1 = w1[(k + 1) * DW_ + c];
        const float wa2 = w1[(k + 2) * DW_ + c];
        const float wa3 = w1[(k + 3) * DW_ + c];
        const float wb0 = w1[(k + 0) * DW_ + c + 128];
        const float wb1 = w1[(k + 1) * DW_ + c + 128];
        const float wb2 = w1[(k + 2) * DW_ + c + 128];
        const float wb3 = w1[(k + 3) * DW_ + c + 128];
        #pragma unroll
        for (int i = 0; i < 4; i++) {
            const float4 s4 = *(const float4*)(&sn[pg * 4 + i][k]);
            acc0[i] += s4.x * wa0 + s4.y * wa1 + s4.z * wa2 + s4.w * wa3;
            acc1[i] += s4.x * wb0 + s4.y * wb1 + s4.z * wb2 + s4.w * wb3;
        }
    }
    const float b1a = b1[c],   b1b = b1[c + 128];
    const float wda = wdw[c],  wdb = wdw[c + 128];
    const float bda = bdw[c],  bdb = bdw[c + 128];
    float gsum = 0.f;
    #pragma unroll
    for (int i = 0; i < 4; i++) {
        const int p = pg * 4 + i;
        const float v0 = (acc0[i] + b1a) * wda + bda;
        const float v1 = (acc1[i] + b1b) * wdb + bdb;
        const float g  = v0 * v1;
        sg_out[(size_t)(pix0 + p) * C_ + c] = g;
        gsum += g;
    }
    gbuf[tid] = gsum;
    __syncthreads();
    if (tid < 128)
        atomicAdd(&gap[batch * C_ + tid], gbuf[tid] + gbuf[tid + 128]);
}

// ---------------------------------------------------------------------------
// SE dense: att[b][d] = (gap[b]/HW) . wse[:,d] + bse[d]
// ---------------------------------------------------------------------------
__global__ __launch_bounds__(128) void k_se(
    const float* __restrict__ gap, const float* __restrict__ wse,
    const float* __restrict__ bse, float* __restrict__ att)
{
    const int b = blockIdx.x;
    const int d = threadIdx.x;
    float acc = bse[d];
    const float inv = 1.0f / (float)HW_;
    for (int cc = 0; cc < C_; cc++)
        acc = fmaf(gap[b * C_ + cc] * inv, wse[cc * C_ + d], acc);
    att[b * C_ + d] = acc;
}

// ---------------------------------------------------------------------------
// Phase 2: sg*att -> w2 matmul -> residual y -> LN2 -> wf1+gate -> wf2 ->
// final output. Reads sg from d_out, overwrites d_out (block-private range).
// ---------------------------------------------------------------------------
__global__ __launch_bounds__(256) void k_phase2(
    const float* __restrict__ x,
    const float* __restrict__ att,
    const float* __restrict__ w2,   const float* __restrict__ b2,
    const float* __restrict__ ln2s, const float* __restrict__ ln2b,
    const float* __restrict__ wf1,  const float* __restrict__ bf1,
    const float* __restrict__ wf2,  const float* __restrict__ bf2,
    const float* __restrict__ beta, const float* __restrict__ gamma,
    float* __restrict__ io)         // in: sg, out: final result
{
    __shared__ float buf1[8][C_];   // sm (sg*att), later cn (LN2 out)
    __shared__ float xb[8][C_];
    __shared__ float yb[8][C_];
    __shared__ float cgb[8][C_];

    const int tid   = threadIdx.x;
    const int pix0  = blockIdx.x * 8;
    const int batch = pix0 / HW_;

    // ---- load sg, apply att; stage x ----
    {
        const int p  = tid >> 5;
        const int c0 = (tid & 31) << 2;
        const float4 g4 = ld4(io + (size_t)(pix0 + p) * C_ + c0);
        const float4 a4 = ld4(att + batch * C_ + c0);
        float4 sm4;
        sm4.x = g4.x * a4.x; sm4.y = g4.y * a4.y;
        sm4.z = g4.z * a4.z; sm4.w = g4.w * a4.w;
        *(float4*)(&buf1[p][c0]) = sm4;
        const float4 x4 = ld4(x + (size_t)(pix0 + p) * C_ + c0);
        *(float4*)(&xb[p][c0]) = x4;
    }
    __syncthreads();

    const int co = tid & 127;
    const int pg = tid >> 7;

    // ---- w2 matmul + residual -> yb ----
    {
        float acc[4] = {0.f, 0.f, 0.f, 0.f};
        for (int k = 0; k < C_; k += 4) {
            const float w0v = w2[(k + 0) * C_ + co];
            const float w1v = w2[(k + 1) * C_ + co];
            const float w2v = w2[(k + 2) * C_ + co];
            const float w3v = w2[(k + 3) * C_ + co];
            #pragma unroll
            for (int i = 0; i < 4; i++) {
                const float4 s4 = *(const float4*)(&buf1[pg * 4 + i][k]);
                acc[i] += s4.x * w0v + s4.y * w1v + s4.z * w2v + s4.w * w3v;
            }
        }
        const float bb = b2[co], be = beta[co];
        #pragma unroll
        for (int i = 0; i < 4; i++) {
            const int p = pg * 4 + i;
            yb[p][co] = xb[p][co] + be * (acc[i] + bb);
        }
    }
    __syncthreads();   // all reads of buf1 (sm) done; yb complete

    // ---- LN2: yb -> buf1 (cn) ----
    {
        const int p  = tid >> 5;
        const int c0 = (tid & 31) << 2;
        const float4 y4 = *(const float4*)(&yb[p][c0]);
        float s  = y4.x + y4.y + y4.z + y4.w;
        float ss = y4.x * y4.x + y4.y * y4.y + y4.z * y4.z + y4.w * y4.w;
        #pragma unroll
        for (int m = 16; m >= 1; m >>= 1) {
            s  += __shfl_xor(s,  m, 32);
            ss += __shfl_xor(ss, m, 32);
        }
        const float mu  = s * (1.0f / C_);
        const float var = ss * (1.0f / C_) - mu * mu;
        const float r   = rsqrtf(var + EPS_);
        const float4 sc = ld4(ln2s + c0);
        const float4 bi = ld4(ln2b + c0);
        float4 o;
        o.x = (y4.x - mu) * r * sc.x + bi.x;
        o.y = (y4.y - mu) * r * sc.y + bi.y;
        o.z = (y4.z - mu) * r * sc.z + bi.z;
        o.w = (y4.w - mu) * r * sc.w + bi.w;
        *(float4*)(&buf1[p][c0]) = o;
    }
    __syncthreads();

    // ---- wf1 matmul + gate -> cgb ----
    {
        float a0[4] = {0.f, 0.f, 0.f, 0.f};
        float a1[4] = {0.f, 0.f, 0.f, 0.f};
        for (int k = 0; k < C_; k += 4) {
            const float wa0 = wf1[(k + 0) * DW_ + co];
            const float wa1 = wf1[(k + 1) * DW_ + co];
            const float wa2 = wf1[(k + 2) * DW_ + co];
            const float wa3 = wf1[(k + 3) * DW_ + co];
            const float wb0 = wf1[(k + 0) * DW_ + co + 128];
            const float wb1 = wf1[(k + 1) * DW_ + co + 128];
            const float wb2 = wf1[(k + 2) * DW_ + co + 128];
            const float wb3 = wf1[(k + 3) * DW_ + co + 128];
            #pragma unroll
            for (int i = 0; i < 4; i++) {
                const float4 s4 = *(const float4*)(&buf1[pg * 4 + i][k]);
                a0[i] += s4.x * wa0 + s4.y * wa1 + s4.z * wa2 + s4.w * wa3;
                a1[i] += s4.x * wb0 + s4.y * wb1 + s4.z * wb2 + s4.w * wb3;
            }
        }
        const float f1a = bf1[co], f1b = bf1[co + 128];
        #pragma unroll
        for (int i = 0; i < 4; i++)
            cgb[pg * 4 + i][co] = (a0[i] + f1a) * (a1[i] + f1b);
    }
    __syncthreads();

    // ---- wf2 matmul + final residual -> io ----
    {
        float acc[4] = {0.f, 0.f, 0.f, 0.f};
        for (int k = 0; k < C_; k += 4) {
            const float w0v = wf2[(k + 0) * C_ + co];
            const float w1v = wf2[(k + 1) * C_ + co];
            const float w2v = wf2[(k + 2) * C_ + co];
            const float w3v = wf2[(k + 3) * C_ + co];
            #pragma unroll
            for (int i = 0; i < 4; i++) {
                const float4 s4 = *(const float4*)(&cgb[pg * 4 + i][k]);
                acc[i] += s4.x * w0v + s4.y * w1v + s4.z * w2v + s4.w * w3v;
            }
        }
        const float fb = bf2[co], gm = gamma[co];
        #pragma unroll
        for (int i = 0; i < 4; i++) {
            const int p = pg * 4 + i;
            io[(size_t)(pix0 + p) * C_ + co] = yb[p][co] + gm * (acc[i] + fb);
        }
    }
}

extern "C" void kernel_launch(void* const* d_in, const int* in_sizes, int n_in,
                              void* d_out, int out_size, void* d_ws, size_t ws_size,
                              hipStream_t stream)
{
    const float* x     = (const float*)d_in[0];
    const float* ln1s  = (const float*)d_in[1];
    const float* ln1b  = (const float*)d_in[2];
    const float* w1    = (const float*)d_in[3];
    const float* b1    = (const float*)d_in[4];
    const float* wdw   = (const float*)d_in[5];
    const float* bdw   = (const float*)d_in[6];
    const float* wse   = (const float*)d_in[7];
    const float* bse   = (const float*)d_in[8];
    const float* w2    = (const float*)d_in[9];
    const float* b2    = (const float*)d_in[10];
    const float* ln2s  = (const float*)d_in[11];
    const float* ln2b  = (const float*)d_in[12];
    const float* wf1   = (const float*)d_in[13];
    const float* bf1   = (const float*)d_in[14];
    const float* wf2   = (const float*)d_in[15];
    const float* bf2   = (const float*)d_in[16];
    const float* beta  = (const float*)d_in[17];
    const float* gamma = (const float*)d_in[18];

    float* out  = (float*)d_out;
    float* gap  = (float*)d_ws;            // [B_][C_]
    float* attb = gap + B_ * C_;           // [B_][C_]

    hipMemsetAsync(gap, 0, B_ * C_ * sizeof(float), stream);
    k_phase1<<<NPIX_ / 8, 256, 0, stream>>>(x, ln1s, ln1b, w1, b1, wdw, bdw, out, gap);
    k_se<<<B_, C_, 0, stream>>>(gap, wse, bse, attb);
    k_phase2<<<NPIX_ / 8, 256, 0, stream>>>(x, attb, w2, b2, ln2s, ln2b,
                                            wf1, bf1, wf2, bf2, beta, gamma, out);
}

// Round 2
// 626.921 us; speedup vs baseline: 2.6344x; 2.6344x over previous
//
#include <hip/hip_runtime.h>
#include <cstddef>

#define C_    128
#define DW_   256
#define HW_   (192 * 192)
#define B_    8
#define NPIX_ (B_ * HW_)
#define EPS_  1e-6f
#define PA_   136            // padded A-tile row stride in bf16 elems (272 B)

typedef __bf16 bf16_t;
typedef __bf16 bf16x8 __attribute__((ext_vector_type(8)));
typedef __bf16 bf16x4 __attribute__((ext_vector_type(4)));
typedef float  f32x4  __attribute__((ext_vector_type(4)));

__device__ __forceinline__ float4 ld4(const float* p) { return *(const float4*)p; }

// ---------------------------------------------------------------------------
// Prep: fold depthwise affine into w1/b1; cast weights to bf16 in B-fragment
// order: flat[((t*4+s)*64+lane)*8 + j] = W[k][n], n = t*16+(lane&15),
// k = s*32 + (lane>>4)*8 + j.  (A/B fragment k-decomposition of 16x16x32.)
// ---------------------------------------------------------------------------
__global__ void k_prep(const float* __restrict__ w1, const float* __restrict__ b1,
                       const float* __restrict__ wdw, const float* __restrict__ bdw,
                       const float* __restrict__ w2, const float* __restrict__ wf1,
                       const float* __restrict__ wf2,
                       bf16_t* __restrict__ wt1, bf16_t* __restrict__ wt2,
                       bf16_t* __restrict__ wtf1, bf16_t* __restrict__ wtf2,
                       float* __restrict__ b1f)
{
    const int id = blockIdx.x * blockDim.x + threadIdx.x;
    const int stride = gridDim.x * blockDim.x;
    for (int n = id; n < DW_; n += stride)
        b1f[n] = b1[n] * wdw[n] + bdw[n];
    for (int f = id; f < 32768; f += stride) {          // w1 (fold wdw), N=256
        const int j = f & 7, lane = (f >> 3) & 63, s = (f >> 9) & 3, t = f >> 11;
        const int n = t * 16 + (lane & 15);
        const int k = s * 32 + ((lane >> 4) << 3) + j;
        wt1[f] = (bf16_t)(w1[k * DW_ + n] * wdw[n]);
    }
    for (int f = id; f < 16384; f += stride) {          // w2, N=128
        const int j = f & 7, lane = (f >> 3) & 63, s = (f >> 9) & 3, t = f >> 11;
        const int n = t * 16 + (lane & 15);
        const int k = s * 32 + ((lane >> 4) << 3) + j;
        wt2[f] = (bf16_t)(w2[k * C_ + n]);
    }
    for (int f = id; f < 32768; f += stride) {          // wf1, N=256
        const int j = f & 7, lane = (f >> 3) & 63, s = (f >> 9) & 3, t = f >> 11;
        const int n = t * 16 + (lane & 15);
        const int k = s * 32 + ((lane >> 4) << 3) + j;
        wtf1[f] = (bf16_t)(wf1[k * DW_ + n]);
    }
    for (int f = id; f < 16384; f += stride) {          // wf2, N=128
        const int j = f & 7, lane = (f >> 3) & 63, s = (f >> 9) & 3, t = f >> 11;
        const int n = t * 16 + (lane & 15);
        const int k = s * 32 + ((lane >> 4) << 3) + j;
        wtf2[f] = (bf16_t)(wf2[k * C_ + n]);
    }
}

// ---------------------------------------------------------------------------
// Phase 1: LN1 -> (w1*wdw) MFMA -> gate -> sg (fp32 to d_out) + gap atomics.
// 64 pixels/block, 4 waves x 16 pixels.
// ---------------------------------------------------------------------------
__global__ __launch_bounds__(256) void k_phase1(
    const float* __restrict__ x,
    const float* __restrict__ ln1s, const float* __restrict__ ln1b,
    const bf16_t* __restrict__ wt1, const float* __restrict__ b1f,
    float* __restrict__ sg_out, float* __restrict__ gap)
{
    __shared__ __align__(16) bf16_t sA[64 * PA_];
    const int tid = threadIdx.x;
    const int pix0 = blockIdx.x * 64;
    const int batch = pix0 / HW_;

    // ---- LN1: 4 threads per pixel, 32 ch each ----
    {
        const int p = tid >> 2, sub = tid & 3;
        const float* xr = x + (size_t)(pix0 + p) * C_ + sub * 32;
        float4 v[8];
        float s = 0.f, ss = 0.f;
        #pragma unroll
        for (int u = 0; u < 8; u++) {
            v[u] = ld4(xr + u * 4);
            s  += v[u].x + v[u].y + v[u].z + v[u].w;
            ss += v[u].x * v[u].x + v[u].y * v[u].y + v[u].z * v[u].z + v[u].w * v[u].w;
        }
        s += __shfl_xor(s, 1); ss += __shfl_xor(ss, 1);
        s += __shfl_xor(s, 2); ss += __shfl_xor(ss, 2);
        const float mu  = s * (1.f / C_);
        const float var = ss * (1.f / C_) - mu * mu;
        const float rr  = rsqrtf(var + EPS_);
        #pragma unroll
        for (int u = 0; u < 8; u++) {
            const int c0 = sub * 32 + u * 4;
            const float4 sc = ld4(ln1s + c0), bi = ld4(ln1b + c0);
            bf16x4 o;
            o[0] = (bf16_t)((v[u].x - mu) * rr * sc.x + bi.x);
            o[1] = (bf16_t)((v[u].y - mu) * rr * sc.y + bi.y);
            o[2] = (bf16_t)((v[u].z - mu) * rr * sc.z + bi.z);
            o[3] = (bf16_t)((v[u].w - mu) * rr * sc.w + bi.w);
            *(bf16x4*)(&sA[p * PA_ + c0]) = o;
        }
    }
    __syncthreads();

    const int lane = tid & 63, wave = tid >> 6;
    const int l15 = lane & 15, quad = lane >> 4;

    bf16x8 af[4];
    #pragma unroll
    for (int s = 0; s < 4; s++)
        af[s] = *(const bf16x8*)(&sA[(wave * 16 + l15) * PA_ + s * 32 + quad * 8]);

    #pragma unroll
    for (int t = 0; t < 8; t++) {
        f32x4 a0 = {0.f, 0.f, 0.f, 0.f};
        f32x4 a1 = {0.f, 0.f, 0.f, 0.f};
        #pragma unroll
        for (int s = 0; s < 4; s++) {
            const bf16x8 b0 = *(const bf16x8*)(wt1 + ((size_t)((t    ) * 4 + s) * 64 + lane) * 8);
            const bf16x8 b1 = *(const bf16x8*)(wt1 + ((size_t)((t + 8) * 4 + s) * 64 + lane) * 8);
            a0 = __builtin_amdgcn_mfma_f32_16x16x32_bf16(af[s], b0, a0, 0, 0, 0);
            a1 = __builtin_amdgcn_mfma_f32_16x16x32_bf16(af[s], b1, a1, 0, 0, 0);
        }
        const float bb0 = b1f[t * 16 + l15], bb1 = b1f[128 + t * 16 + l15];
        float gs = 0.f;
        #pragma unroll
        for (int r = 0; r < 4; r++) {
            const float g = (a0[r] + bb0) * (a1[r] + bb1);
            const int p = pix0 + wave * 16 + quad * 4 + r;
            sg_out[(size_t)p * C_ + t * 16 + l15] = g;
            gs += g;
        }
        gs += __shfl_xor(gs, 16);
        gs += __shfl_xor(gs, 32);
        if (lane < 16)
            atomicAdd(&gap[batch * C_ + t * 16 + lane], gs);
    }
}

// ---------------------------------------------------------------------------
// SE dense: att[b][d] = (gap[b]/HW) . wse[:,d] + bse[d]
// ---------------------------------------------------------------------------
__global__ __launch_bounds__(128) void k_se(
    const float* __restrict__ gap, const float* __restrict__ wse,
    const float* __restrict__ bse, float* __restrict__ att)
{
    const int b = blockIdx.x;
    const int d = threadIdx.x;
    float acc = bse[d];
    const float inv = 1.0f / (float)HW_;
    for (int cc = 0; cc < C_; cc++)
        acc = fmaf(gap[b * C_ + cc] * inv, wse[cc * C_ + d], acc);
    att[b * C_ + d] = acc;
}

// ---------------------------------------------------------------------------
// Phase 2: sm=sg*att -> w2 MFMA -> y -> LN2 -> wf1 MFMA + gate -> wf2 MFMA ->
// out. 64 pixels/block.
// ---------------------------------------------------------------------------
__global__ __launch_bounds__(256) void k_phase2(
    const float* __restrict__ x, const float* __restrict__ att,
    const bf16_t* __restrict__ wt2, const float* __restrict__ b2,
    const float* __restrict__ ln2s, const float* __restrict__ ln2b,
    const bf16_t* __restrict__ wtf1, const float* __restrict__ bf1,
    const bf16_t* __restrict__ wtf2, const float* __restrict__ bf2,
    const float* __restrict__ beta, const float* __restrict__ gamma,
    float* __restrict__ io)
{
    __shared__ __align__(16) bf16_t sA[64 * PA_];          // sm, then cn
    __shared__ __align__(16) float  ybuf[64 * 132];        // y fp32; later cg bf16
    bf16_t* cgb = (bf16_t*)ybuf;

    const int tid = threadIdx.x;
    const int pix0 = blockIdx.x * 64;
    const int batch = pix0 / HW_;

    // ---- sm = sg * att -> sA (bf16) ----
    {
        const int p = tid >> 2, sub = tid & 3;
        const float* gr = io + (size_t)(pix0 + p) * C_ + sub * 32;
        const float* ar = att + batch * C_ + sub * 32;
        #pragma unroll
        for (int u = 0; u < 8; u++) {
            const float4 g = ld4(gr + u * 4), a = ld4(ar + u * 4);
            bf16x4 o;
            o[0] = (bf16_t)(g.x * a.x);
            o[1] = (bf16_t)(g.y * a.y);
            o[2] = (bf16_t)(g.z * a.z);
            o[3] = (bf16_t)(g.w * a.w);
            *(bf16x4*)(&sA[p * PA_ + sub * 32 + u * 4]) = o;
        }
    }
    __syncthreads();

    const int lane = tid & 63, wave = tid >> 6;
    const int l15 = lane & 15, quad = lane >> 4;
    float yreg[32];

    // ---- w2 GEMM + residual -> yreg + ybuf ----
    {
        bf16x8 af[4];
        #pragma unroll
        for (int s = 0; s < 4; s++)
            af[s] = *(const bf16x8*)(&sA[(wave * 16 + l15) * PA_ + s * 32 + quad * 8]);
        #pragma unroll
        for (int t = 0; t < 8; t++) {
            f32x4 acc = {0.f, 0.f, 0.f, 0.f};
            #pragma unroll
            for (int s = 0; s < 4; s++) {
                const bf16x8 b = *(const bf16x8*)(wt2 + ((size_t)(t * 4 + s) * 64 + lane) * 8);
                acc = __builtin_amdgcn_mfma_f32_16x16x32_bf16(af[s], b, acc, 0, 0, 0);
            }
            const int n = t * 16 + l15;
            const float b2n = b2[n], bta = beta[n];
            #pragma unroll
            for (int r = 0; r < 4; r++) {
                const int m = wave * 16 + quad * 4 + r;
                const float xv = x[(size_t)(pix0 + m) * C_ + n];
                const float yv = xv + bta * (acc[r] + b2n);
                yreg[t * 4 + r] = yv;
                ybuf[m * 132 + n] = yv;
            }
        }
    }
    __syncthreads();

    // ---- LN2: ybuf -> sA (cn bf16) ----
    {
        const int p = tid >> 2, sub = tid & 3;
        float4 v[8];
        float s = 0.f, ss = 0.f;
        #pragma unroll
        for (int u = 0; u < 8; u++) {
            v[u] = *(const float4*)(&ybuf[p * 132 + sub * 32 + u * 4]);
            s  += v[u].x + v[u].y + v[u].z + v[u].w;
            ss += v[u].x * v[u].x + v[u].y * v[u].y + v[u].z * v[u].z + v[u].w * v[u].w;
        }
        s += __shfl_xor(s, 1); ss += __shfl_xor(ss, 1);
        s += __shfl_xor(s, 2); ss += __shfl_xor(ss, 2);
        const float mu  = s * (1.f / C_);
        const float var = ss * (1.f / C_) - mu * mu;
        const float rr  = rsqrtf(var + EPS_);
        #pragma unroll
        for (int u = 0; u < 8; u++) {
            const int c0 = sub * 32 + u * 4;
            const float4 sc = ld4(ln2s + c0), bi = ld4(ln2b + c0);
            bf16x4 o;
            o[0] = (bf16_t)((v[u].x - mu) * rr * sc.x + bi.x);
            o[1] = (bf16_t)((v[u].y - mu) * rr * sc.y + bi.y);
            o[2] = (bf16_t)((v[u].z - mu) * rr * sc.z + bi.z);
            o[3] = (bf16_t)((v[u].w - mu) * rr * sc.w + bi.w);
            *(bf16x4*)(&sA[p * PA_ + c0]) = o;
        }
    }
    __syncthreads();   // cn ready; ybuf dead -> reusable as cgb

    // ---- wf1 GEMM + gate -> cgb (bf16) ----
    {
        bf16x8 af[4];
        #pragma unroll
        for (int s = 0; s < 4; s++)
            af[s] = *(const bf16x8*)(&sA[(wave * 16 + l15) * PA_ + s * 32 + quad * 8]);
        #pragma unroll
        for (int t = 0; t < 8; t++) {
            f32x4 a0 = {0.f, 0.f, 0.f, 0.f};
            f32x4 a1 = {0.f, 0.f, 0.f, 0.f};
            #pragma unroll
            for (int s = 0; s < 4; s++) {
                const bf16x8 b0 = *(const bf16x8*)(wtf1 + ((size_t)((t    ) * 4 + s) * 64 + lane) * 8);
                const bf16x8 b1 = *(const bf16x8*)(wtf1 + ((size_t)((t + 8) * 4 + s) * 64 + lane) * 8);
                a0 = __builtin_amdgcn_mfma_f32_16x16x32_bf16(af[s], b0, a0, 0, 0, 0);
                a1 = __builtin_amdgcn_mfma_f32_16x16x32_bf16(af[s], b1, a1, 0, 0, 0);
            }
            const float f1a = bf1[t * 16 + l15], f1b = bf1[128 + t * 16 + l15];
            #pragma unroll
            for (int r = 0; r < 4; r++) {
                const float cg = (a0[r] + f1a) * (a1[r] + f1b);
                cgb[(wave * 16 + quad * 4 + r) * PA_ + t * 16 + l15] = (bf16_t)cg;
            }
        }
    }
    __syncthreads();

    // ---- wf2 GEMM + final residual -> io ----
    {
        bf16x8 af[4];
        #pragma unroll
        for (int s = 0; s < 4; s++)
            af[s] = *(const bf16x8*)(&cgb[(wave * 16 + l15) * PA_ + s * 32 + quad * 8]);
        #pragma unroll
        for (int t = 0; t < 8; t++) {
            f32x4 acc = {0.f, 0.f, 0.f, 0.f};
            #pragma unroll
            for (int s = 0; s < 4; s++) {
                const bf16x8 b = *(const bf16x8*)(wtf2 + ((size_t)(t * 4 + s) * 64 + lane) * 8);
                acc = __builtin_amdgcn_mfma_f32_16x16x32_bf16(af[s], b, acc, 0, 0, 0);
            }
            const int n = t * 16 + l15;
            const float fb = bf2[n], gm = gamma[n];
            #pragma unroll
            for (int r = 0; r < 4; r++) {
                const int m = wave * 16 + quad * 4 + r;
                io[(size_t)(pix0 + m) * C_ + n] = yreg[t * 4 + r] + gm * (acc[r] + fb);
            }
        }
    }
}

extern "C" void kernel_launch(void* const* d_in, const int* in_sizes, int n_in,
                              void* d_out, int out_size, void* d_ws, size_t ws_size,
                              hipStream_t stream)
{
    const float* x     = (const float*)d_in[0];
    const float* ln1s  = (const float*)d_in[1];
    const float* ln1b  = (const float*)d_in[2];
    const float* w1    = (const float*)d_in[3];
    const float* b1    = (const float*)d_in[4];
    const float* wdw   = (const float*)d_in[5];
    const float* bdw   = (const float*)d_in[6];
    const float* wse   = (const float*)d_in[7];
    const float* bse   = (const float*)d_in[8];
    const float* w2    = (const float*)d_in[9];
    const float* b2    = (const float*)d_in[10];
    const float* ln2s  = (const float*)d_in[11];
    const float* ln2b  = (const float*)d_in[12];
    const float* wf1   = (const float*)d_in[13];
    const float* bf1   = (const float*)d_in[14];
    const float* wf2   = (const float*)d_in[15];
    const float* bf2   = (const float*)d_in[16];
    const float* beta  = (const float*)d_in[17];
    const float* gamma = (const float*)d_in[18];

    float* out = (float*)d_out;
    char*  ws  = (char*)d_ws;
    float*  gap  = (float*)(ws);                 // 1024 f = 4 KB
    float*  attb = (float*)(ws + 4096);          // 1024 f = 4 KB
    float*  b1f  = (float*)(ws + 8192);          // 256 f  = 1 KB
    bf16_t* wt1  = (bf16_t*)(ws + 12288);        // 64 KB
    bf16_t* wt2  = (bf16_t*)(ws + 77824);        // 32 KB
    bf16_t* wtf1 = (bf16_t*)(ws + 110592);       // 64 KB
    bf16_t* wtf2 = (bf16_t*)(ws + 176128);       // 32 KB

    k_prep<<<192, 256, 0, stream>>>(w1, b1, wdw, bdw, w2, wf1, wf2,
                                    wt1, wt2, wtf1, wtf2, b1f);
    hipMemsetAsync(gap, 0, B_ * C_ * sizeof(float), stream);
    k_phase1<<<NPIX_ / 64, 256, 0, stream>>>(x, ln1s, ln1b, wt1, b1f, out, gap);
    k_se<<<B_, C_, 0, stream>>>(gap, wse, bse, attb);
    k_phase2<<<NPIX_ / 64, 256, 0, stream>>>(x, attb, wt2, b2, ln2s, ln2b,
                                             wtf1, bf1, wtf2, bf2, beta, gamma, out);
}